// Round 3
// baseline (349.455 us; speedup 1.0000x reference)
//
#include <hip/hip_runtime.h>
#include <hip/hip_bf16.h>

#define N_NODES 50000
#define N_EDGES 1000000
#define C       128
#define N_REL   8
#define N_SEG   (N_NODES * N_REL)       // 400000
#define KTOT    (N_REL * C + C)         // 1152 = 8 rel chunks + self
#define KC_CNT  (KTOT / 32)             // 36 MFMA k-chunks
#define A_STRIDE 1160                   // 1152 + 8 bf16 pad per row
#define NCHUNK  ((N_SEG + 1023) / 1024) // 391 scan chunks
#define MV_N    (N_SEG + 1 + N_EDGES)   // 1,400,001 ints to relocate
#define MROW    32                      // nodes per layer block
#define NBLK    ((N_NODES + MROW - 1) / MROW)   // 1563 (last block: 16 real rows)
#define FE_BLK  ((N_EDGES + 511) / 512) // 1954 fill edge-blocks

typedef __hip_bfloat16  bf16;
typedef __hip_bfloat162 bf162;
typedef __attribute__((ext_vector_type(8))) short short8;
typedef __attribute__((ext_vector_type(4))) float f32x4;
typedef __attribute__((ext_vector_type(2))) float f32x2;

// ---------------------------------------------------------------- weight fragment index
// B-fragment for mfma_f32_16x16x32_bf16: lane = quad*16 + (n&15) holds
// B[k = kc*32 + quad*8 + j][n], j=0..7 contiguous.
__device__ __forceinline__ size_t frag_index(int k, int n) {
    int nt = n >> 4, n15 = n & 15;
    int kc = k >> 5, quad = (k >> 3) & 3, j = k & 7;
    int lane = quad * 16 + n15;
    return ((size_t)(nt * KC_CNT + kc) * 64 + lane) * 8 + j;
}

// ---------------------------------------------------------------- prep: x->bf16 cvt + seg count
// The count atomic's RETURN VALUE is the within-segment rank -- stored
// (coalesced) so fillB needs no second (ticket) atomic.
#define CVT_BLOCKS ((N_NODES * C / 2) / 256)          // 12500 (exact)
#define CNT_BLOCKS ((N_EDGES + 255) / 256)            // 3907
__global__ void prep_kernel(const float2* __restrict__ xf, unsigned int* __restrict__ xb,
                            const int* __restrict__ dst, const int* __restrict__ et,
                            int* __restrict__ cnt, int* __restrict__ rank) {
    int bid = blockIdx.x;
    if (bid < CVT_BLOCKS) {
        int i = bid * 256 + threadIdx.x;
        float2 v = xf[i];
        union { bf162 h; unsigned int u; } cv;
        cv.h = bf162(__float2bfloat16(v.x), __float2bfloat16(v.y));
        xb[i] = cv.u;
    } else {
        int e = (bid - CVT_BLOCKS) * 256 + threadIdx.x;
        if (e < N_EDGES) rank[e] = atomicAdd(&cnt[dst[e] * N_REL + et[e]], 1);
    }
}

// ---------------------------------------------------------------- scanA: chunk scans + weight repack
#define RP_B  (KTOT * C / 256)            // 576
#define RPT_B ((KTOT / 16) * (C / 16))    // 72 * 8 = 576
__global__ void scanA_kernel(const int* __restrict__ cnt, int* __restrict__ offs,
                             int* __restrict__ partials,
                             const float* __restrict__ W1, const float* __restrict__ root1,
                             const float* __restrict__ W2, const float* __restrict__ root2,
                             const float* __restrict__ linW,
                             const float* __restrict__ b2, const float* __restrict__ linb,
                             bf16* __restrict__ Bp1, bf16* __restrict__ Bp2,
                             float* __restrict__ b2p) {
    int bid = blockIdx.x;
    int t   = threadIdx.x;
    if (bid < NCHUNK) {
        __shared__ int tot[256];
        int base = bid * 1024 + t * 4;
        int v0 = (base + 0 < N_SEG) ? cnt[base + 0] : 0;
        int v1 = (base + 1 < N_SEG) ? cnt[base + 1] : 0;
        int v2 = (base + 2 < N_SEG) ? cnt[base + 2] : 0;
        int v3 = (base + 3 < N_SEG) ? cnt[base + 3] : 0;
        int tsum = v0 + v1 + v2 + v3;
        tot[t] = tsum;
        __syncthreads();
        for (int d = 1; d < 256; d <<= 1) {
            int x = tot[t];
            int y = (t >= d) ? tot[t - d] : 0;
            __syncthreads();
            tot[t] = x + y;
            __syncthreads();
        }
        int excl = tot[t] - tsum;
        if (base + 0 < N_SEG) offs[base + 0] = excl;
        if (base + 1 < N_SEG) offs[base + 1] = excl + v0;
        if (base + 2 < N_SEG) offs[base + 2] = excl + v0 + v1;
        if (base + 3 < N_SEG) offs[base + 3] = excl + v0 + v1 + v2;
        if (t == 255) partials[bid] = tot[255];
    } else if (bid < NCHUNK + RP_B) {
        int idx = (bid - NCHUNK) * 256 + t;
        int k = idx >> 7, n = idx & 127;
        float val;
        if (k < N_REL * C) val = W1[(size_t)k * C + n];
        else               val = root1[(size_t)(k - N_REL * C) * C + n];
        Bp1[frag_index(k, n)] = __float2bfloat16(val);
    } else if (bid < NCHUNK + RP_B + RPT_B) {
        // ---- tiled repack2: out(k0+ty, n0+tx) = sum_m W2cat[k0+ty][m] * linW[m][n0+tx]
        __shared__ float Wt[16][128];    // 8 KB
        __shared__ float Lt[128][16];    // 8 KB
        int tileid = bid - NCHUNK - RP_B;
        int kt = tileid >> 3;            // 0..71  (k0 = kt*16; 1024 boundary not straddled)
        int n0 = (tileid & 7) * 16;
        int k0 = kt * 16;
        const float* baseW = (k0 < N_REL * C) ? (W2 + (size_t)k0 * C)
                                              : (root2 + (size_t)(k0 - N_REL * C) * C);
#pragma unroll
        for (int r = 0; r < 8; r++) {            // 2048 elems, coalesced
            int idx = t + r * 256;
            Wt[idx >> 7][idx & 127] = baseW[idx];
        }
#pragma unroll
        for (int r = 0; r < 8; r++) {            // 2048 elems: m = idx>>4, n = idx&15
            int idx = t + r * 256;
            Lt[idx >> 4][idx & 15] = linW[(size_t)(idx >> 4) * C + n0 + (idx & 15)];
        }
        __syncthreads();
        int ty = t >> 4, tx = t & 15;
        float acc = 0.f;
#pragma unroll 8
        for (int m = 0; m < 128; m++)
            acc += Wt[ty][m] * Lt[m][tx];
        Bp2[frag_index(k0 + ty, n0 + tx)] = __float2bfloat16(acc);
    } else {
        if (t < 128) {
            float acc = linb[t];
            for (int m = 0; m < C; m++)
                acc += b2[m] * linW[(size_t)m * C + t];
            b2p[t] = acc;
        }
    }
}

// ---------------------------------------------------------------- fillB: offs finalize + edge fill
__global__ void fillB_kernel(const int* __restrict__ src, const int* __restrict__ dst,
                             const int* __restrict__ et,
                             const int* __restrict__ offs_raw,   // scanA output
                             const int* __restrict__ partials,
                             int* __restrict__ offs_final,
                             const int* __restrict__ rank,
                             int* __restrict__ srcs_out) {
    __shared__ int s[512];
    int t = threadIdx.x;
    int bid = blockIdx.x;
    s[t] = (t < NCHUNK) ? partials[t] : 0;
    __syncthreads();
    for (int d = 1; d < 512; d <<= 1) {
        int x = s[t];
        int y = (t >= d) ? s[t - d] : 0;
        __syncthreads();
        s[t] = x + y;          // inclusive scan
        __syncthreads();
    }
    if (bid < NCHUNK) {
        int add = (bid == 0) ? 0 : s[bid - 1];
        int base = bid * 1024 + t * 2;
#pragma unroll
        for (int j = 0; j < 2; j++) {
            int idx = base + j;
            if (idx < N_SEG) offs_final[idx] = offs_raw[idx] + add;
        }
        if (bid == 0 && t == 0) offs_final[N_SEG] = N_EDGES;
    } else {
        int e = (bid - NCHUNK) * 512 + t;
        if (e < N_EDGES) {
            int seg = dst[e] * N_REL + et[e];
            int chunk = seg >> 10;
            int base = offs_raw[seg] + ((chunk == 0) ? 0 : s[chunk - 1]);
            srcs_out[base + rank[e]] = src[e];
        }
    }
}

// ---------------------------------------------------------------- fused layer
// R13 structure: 32 nodes/block, 512 threads (8 waves).
//   Aggregation: wave w owns local segments [32w, 32w+32); CSR offsets held
//   lane-wise in a register (readlane, no LDS chain); gather pipeline DEPTH 3
//   (48 edges in flight per wave).
//   GEMM: wave w = (node-half w>>2, col-pair w&3) computes 16 nodes x 32 cols.
//   Each wave reads ONLY its 16-node half of the A tile -> A-LDS read traffic
//   halves vs R12 (8x -> 4x amplification; targets the 56k cy/CU LDS pipe
//   serialization + the invariant 3.6M bank-conflict counter).
template <int RELU, int OUT_F32, int COPY_CSR>
__global__ __launch_bounds__(512, 4) void fused_layer(
        const unsigned int* __restrict__ featu,  // [N][64] bf16 pairs
        const int*   __restrict__ offs,          // [N_SEG+1]
        const int*   __restrict__ srcs,          // [N_EDGES]
        const short8* __restrict__ Bp,           // fragment-packed bf16 weights
        const float* __restrict__ bias,          // [128] fp32
        void* __restrict__ outp,                 // [N][128] fp32 or bf16
        int* __restrict__ offs2, int* __restrict__ srcs2)   // CSR copy dst
{
    __shared__ __align__(16) unsigned int At[MROW * (A_STRIDE / 2)];  // 74,240 B
    const int tid  = threadIdx.x;
    const int lane = tid & 63;
    const int w    = tid >> 6;          // 0..7
    const int v0   = blockIdx.x * MROW;

    // pad pairs (k range [1152..1159) as bf16 -> 4 uint pairs per row)
    if (tid < 4 * MROW) At[(tid >> 2) * (A_STRIDE / 2) + 576 + (tid & 3)] = 0u;

    // relocate CSR slice (overlapped with gather latency)
    if (COPY_CSR) {
        for (int i = blockIdx.x * 512 + tid; i < MV_N; i += NBLK * 512) {
            if (i < N_SEG + 1) offs2[i] = offs[i];
            else               srcs2[i - (N_SEG + 1)] = srcs[i - (N_SEG + 1)];
        }
    }

    // self rows -> k range [1024..1151]
    for (int q = tid; q < MROW * 64; q += 512) {
        int node = q >> 6, pch = q & 63;
        unsigned int sval = 0u;
        if (v0 + node < N_NODES) sval = featu[(size_t)(v0 + node) * 64 + pch];
        At[node * (A_STRIDE / 2) + 512 + pch] = sval;
    }

    // ---- aggregation over wave-owned contiguous edge range (32 segments)
    {
        const int segLo   = w * 32;                 // block-local 0..224
        const int segBase = v0 * 8 + segLo;         // global segment index
        // wave's 33 offsets, held lane-wise in ONE register (clamped reads)
        int oidx = segBase + ((lane < 32) ? lane : 32);
        if (oidx > N_SEG) oidx = N_SEG;
        const int offsReg = offs[oidx];
#define OFFS(L) __builtin_amdgcn_readlane(offsReg, (L))

        int curSeg = segLo;                          // block-local
        int i      = OFFS(0);                        // scalar
        int segBeg = i;
        int segEnd = OFFS(1);
        const int eend = OFFS(32);
        f32x2 acc2 = {0.f, 0.f};

        // flush all segments ending exactly at edge index 'upto' (scalar loop)
        auto FLUSH = [&](int upto) {
            while (segEnd == upto) {
                float inv = (segEnd > segBeg) ? 1.0f / (float)(segEnd - segBeg) : 0.0f;
                union { bf162 h; unsigned int u; } cv;
                cv.h = bf162(__float2bfloat16(acc2.x * inv), __float2bfloat16(acc2.y * inv));
                At[(curSeg >> 3) * (A_STRIDE / 2) + (curSeg & 7) * 64 + lane] = cv.u;
                acc2.x = 0.f; acc2.y = 0.f;
                segBeg = segEnd;
                curSeg++;
                segEnd = OFFS(curSeg + 1 - segLo);   // readlane, no LDS
            }
        };
        auto LOADF = [&](unsigned int (&v)[16], int base) {    // base is scalar
            int sv[16];
#pragma unroll
            for (int j = 0; j < 16; j++) sv[j] = srcs[base + j];
#pragma unroll
            for (int j = 0; j < 16; j++) v[j] = featu[(size_t)sv[j] * 64 + lane];
        };
        auto FOLD16 = [&](unsigned int (&v)[16]) {
#pragma unroll
            for (int j = 0; j < 16; j++) {
                FLUSH(i + j);
                union { unsigned int u; float f; } lo, hi;
                lo.u = v[j] << 16;
                hi.u = v[j] & 0xFFFF0000u;
                f32x2 tadd = {lo.f, hi.f};
                acc2 += tadd;
            }
            i += 16;
        };

        unsigned int vA[16], vB[16], vC[16];
        const int nfull = (eend - i) >> 4;          // scalar batch count
        if (nfull > 0) {
            LOADF(vA, i);
            if (nfull > 1) LOADF(vB, i + 16);
            int b = 0;
            while (true) {                          // uniform control, depth-3 rotation
                if (b + 2 < nfull) LOADF(vC, i + 32);
                FOLD16(vA);
                b++; if (b >= nfull) break;
                if (b + 2 < nfull) LOADF(vA, i + 32);
                FOLD16(vB);
                b++; if (b >= nfull) break;
                if (b + 2 < nfull) LOADF(vB, i + 32);
                FOLD16(vC);
                b++; if (b >= nfull) break;
            }
        }
        // tail batch (m < 16, scalar m -> uniform branches)
        {
            const int m = eend - i;
            if (m > 0) {
                int sv[16];
#pragma unroll
                for (int j = 0; j < 16; j++) if (j < m) sv[j] = srcs[i + j];
#pragma unroll
                for (int j = 0; j < 16; j++) if (j < m) vA[j] = featu[(size_t)sv[j] * 64 + lane];
#pragma unroll
                for (int j = 0; j < 16; j++) {
                    if (j < m) {
                        FLUSH(i + j);
                        union { unsigned int u; float f; } lo, hi;
                        lo.u = vA[j] << 16;
                        hi.u = vA[j] & 0xFFFF0000u;
                        f32x2 tadd = {lo.f, hi.f};
                        acc2 += tadd;
                    }
                }
            }
        }
        // trailing flushes (last non-empty segment + empty tails)
        while (curSeg < segLo + 32) {
            float inv = (segEnd > segBeg) ? 1.0f / (float)(segEnd - segBeg) : 0.0f;
            union { bf162 h; unsigned int u; } cv;
            cv.h = bf162(__float2bfloat16(acc2.x * inv), __float2bfloat16(acc2.y * inv));
            At[(curSeg >> 3) * (A_STRIDE / 2) + (curSeg & 7) * 64 + lane] = cv.u;
            acc2.x = 0.f; acc2.y = 0.f;
            segBeg = segEnd;
            curSeg++;
            if (curSeg < segLo + 32)
                segEnd = OFFS(curSeg + 1 - segLo);
        }
#undef OFFS
    }
    __syncthreads();

    // ---- MFMA GEMM: wave (wh = w>>2, wc = w&3): nodes [16wh,16wh+16),
    //      cols [32wc, 32wc+32). One A-read feeds 2 MFMAs; A traffic halved.
    const int quad = lane >> 4, n15 = lane & 15;
    const int wh = w >> 2;
    const int wc = w & 3;
    f32x4 acc0 = {0.f, 0.f, 0.f, 0.f};
    f32x4 acc1 = {0.f, 0.f, 0.f, 0.f};
    const short* Ash = (const short*)At;
    const short8* BpT0 = Bp + (size_t)(2 * wc)     * KC_CNT * 64;
    const short8* BpT1 = Bp + (size_t)(2 * wc + 1) * KC_CNT * 64;
    const short* arow = Ash + (n15 + 16 * wh) * A_STRIDE + quad * 8;

    short8 b0 = BpT0[lane];
    short8 b1 = BpT1[lane];
    __builtin_amdgcn_s_setprio(1);
#pragma unroll 4
    for (int kc = 0; kc < KC_CNT; kc++) {
        short8 cb0 = b0, cb1 = b1;
        if (kc + 1 < KC_CNT) {
            b0 = BpT0[(kc + 1) * 64 + lane];
            b1 = BpT1[(kc + 1) * 64 + lane];
        }
        short8 a = *reinterpret_cast<const short8*>(arow + kc * 32);
        acc0 = __builtin_amdgcn_mfma_f32_16x16x32_bf16(a, cb0, acc0, 0, 0, 0);
        acc1 = __builtin_amdgcn_mfma_f32_16x16x32_bf16(a, cb1, acc1, 0, 0, 0);
    }
    __builtin_amdgcn_s_setprio(0);

    // epilogue: node = v0 + wh*16 + quad*4 + r; cols wc*32+n15 and +16
    {
        int col0 = wc * 32 + n15;
        int col1 = col0 + 16;
        float bv0 = bias[col0], bv1 = bias[col1];
        int nodeBase = v0 + wh * 16 + quad * 4;
#pragma unroll
        for (int r = 0; r < 4; r++) {
            int node = nodeBase + r;
            if (node < N_NODES) {
                float va = acc0[r] + bv0;
                float vb = acc1[r] + bv1;
                if (RELU) { va = fmaxf(va, 0.f); vb = fmaxf(vb, 0.f); }
                if (OUT_F32) {
                    ((float*)outp)[(size_t)node * C + col0] = va;
                    ((float*)outp)[(size_t)node * C + col1] = vb;
                } else {
                    ((bf16*)outp)[(size_t)node * C + col0] = __float2bfloat16(va);
                    ((bf16*)outp)[(size_t)node * C + col1] = __float2bfloat16(vb);
                }
            }
        }
    }
}

// ---------------------------------------------------------------- launch
// fp32 I/O. ZERO d_ws usage. Provenance:
//   d_out lo   : CSR scratch. offs_final ALIASES cnt (cnt dead after scanA;
//                fillB writes it after scanA completes -- stream ordered).
//   d_out mid  : rank [N_EDGES] (written by prep, read by fillB)
//   d_out hi   : x as bf16 (12.8 MB @ +11,202,048, 256B-ALIGNED) [dead after layer 1]
//   x buffer lo: h1 bf16 (12.8 MB)                            [x fp32 dead after cvt]
//   x buffer hi: packed weights Bp1/Bp2/b2p (@ +13.0 MB)      [written in scanA]
//   ei buffer  : final CSR (offs2+srcs2), copied BY layer 1   [ei dead after fillB]
//   d_out      : final fp32 output (layer 2 writes directly)
extern "C" void kernel_launch(void* const* d_in, const int* in_sizes, int n_in,
                              void* d_out, int out_size, void* d_ws, size_t ws_size,
                              hipStream_t stream) {
    const float* x     = (const float*)d_in[0];
    const int*   ei    = (const int*)d_in[1];
    const int*   et    = (const int*)d_in[2];
    const float* W1    = (const float*)d_in[3];
    const float* root1 = (const float*)d_in[4];
    const float* b1    = (const float*)d_in[5];
    const float* W2    = (const float*)d_in[6];
    const float* root2 = (const float*)d_in[7];
    const float* b2    = (const float*)d_in[8];
    const float* linW  = (const float*)d_in[9];
    const float* linb  = (const float*)d_in[10];
    const int* src = ei;
    const int* dst = ei + N_EDGES;

    // ---- d_out scratch
    char* ob = (char*)d_out;
    int* cnt_i    = (int*)(ob + 0);          // 1,600,000 B (memset)
    int* offs_f   = (int*)(ob + 0);          // [N_SEG+1] -- aliases cnt (dead after scanA)
    int* offs_t   = (int*)(ob + 1600256);    // 1,600,000 B (raw chunk-local scans)
    int* partials = (int*)(ob + 3200256);    // 1,564 B
    int* srcs_t   = (int*)(ob + 3202048);    // 4,000,000 B -> ends 7,202,048
    int* rank     = (int*)(ob + 7202048);    // 4,000,000 B -> ends 11,202,048
    unsigned int* xb16 = (unsigned int*)(ob + 11202048); // 256B-aligned; ends 24,002,048 < 25.6 MB

    // ---- ei buffer: final CSR (written by layer 1's copy slice)
    char* eb = (char*)d_in[1];
    int* offs2 = (int*)(eb + 0);
    int* srcs2 = (int*)(eb + 1600256);       // ends 5,600,256 < 8 MB

    // ---- x buffer: h1 low, weights high
    char* xbuf = (char*)d_in[0];
    unsigned int* h1 = (unsigned int*)xbuf;          // 12.8 MB
    bf16*  Bp1 = (bf16*)(xbuf + 13000192);           // 16B-aligned, 294,912 B
    bf16*  Bp2 = (bf16*)(xbuf + 13295360);           // 294,912 B
    float* b2p = (float*)(xbuf + 13590528);          // 512 B -> ends < 25.6 MB

    float* out = (float*)d_out;

    hipMemsetAsync(cnt_i, 0, 1600000, stream);   // cnt only
    prep_kernel<<<CVT_BLOCKS + CNT_BLOCKS, 256, 0, stream>>>(
        (const float2*)x, xb16, dst, et, cnt_i, rank);
    scanA_kernel<<<NCHUNK + RP_B + RPT_B + 1, 256, 0, stream>>>(
        cnt_i, offs_t, partials, W1, root1, W2, root2, linW, b2, linb,
        Bp1, Bp2, b2p);
    fillB_kernel<<<NCHUNK + FE_BLK, 512, 0, stream>>>(
        src, dst, et, offs_t, partials, offs_f, rank, srcs_t);

    fused_layer<1, 0, 1><<<NBLK, 512, 0, stream>>>(
        xb16, offs_f, srcs_t, (const short8*)Bp1, b1, (void*)h1, offs2, srcs2);
    fused_layer<0, 1, 0><<<NBLK, 512, 0, stream>>>(
        h1, offs2, srcs2, (const short8*)Bp2, b2p, (void*)out, nullptr, nullptr);

    (void)in_sizes; (void)n_in; (void)out_size; (void)d_ws; (void)ws_size;
}

// Round 4
// 296.834 us; speedup vs baseline: 1.1773x; 1.1773x over previous
//
#include <hip/hip_runtime.h>
#include <hip/hip_bf16.h>

#define N_NODES 50000
#define N_EDGES 1000000
#define C       128
#define N_REL   8
#define N_SEG   (N_NODES * N_REL)       // 400000
#define KTOT    (N_REL * C + C)         // 1152 = 8 rel chunks + self
#define KC_CNT  (KTOT / 32)             // 36 MFMA k-chunks
#define A_STRIDE 1160                   // 1152 + 8 bf16 pad per row
#define NCHUNK  ((N_SEG + 1023) / 1024) // 391 scan chunks
#define MV_N    (N_SEG + 1 + N_EDGES)   // 1,400,001 ints to relocate
#define NBLK    (N_NODES / 16)          // 3125 layer blocks
#define FE_BLK  ((N_EDGES + 511) / 512) // 1954 fill edge-blocks

typedef __hip_bfloat16  bf16;
typedef __hip_bfloat162 bf162;
typedef __attribute__((ext_vector_type(8))) short short8;
typedef __attribute__((ext_vector_type(4))) float f32x4;

// ---------------------------------------------------------------- weight fragment index
// B-fragment for mfma_f32_16x16x32_bf16: lane = quad*16 + (n&15) holds
// B[k = kc*32 + quad*8 + j][n], j=0..7 contiguous.
__device__ __forceinline__ size_t frag_index(int k, int n) {
    int nt = n >> 4, n15 = n & 15;
    int kc = k >> 5, quad = (k >> 3) & 3, j = k & 7;
    int lane = quad * 16 + n15;
    return ((size_t)(nt * KC_CNT + kc) * 64 + lane) * 8 + j;
}

// ---------------------------------------------------------------- prep: x->bf16 cvt + seg count
// The count atomic's RETURN VALUE is the within-segment rank -- stored
// (coalesced) so fillB needs no second (ticket) atomic.
#define CVT_BLOCKS ((N_NODES * C / 2) / 256)          // 12500 (exact)
#define CNT_BLOCKS ((N_EDGES + 255) / 256)            // 3907
__global__ void prep_kernel(const float2* __restrict__ xf, unsigned int* __restrict__ xb,
                            const int* __restrict__ dst, const int* __restrict__ et,
                            int* __restrict__ cnt, int* __restrict__ rank) {
    int bid = blockIdx.x;
    if (bid < CVT_BLOCKS) {
        int i = bid * 256 + threadIdx.x;
        float2 v = xf[i];
        union { bf162 h; unsigned int u; } cv;
        cv.h = bf162(__float2bfloat16(v.x), __float2bfloat16(v.y));
        xb[i] = cv.u;
    } else {
        int e = (bid - CVT_BLOCKS) * 256 + threadIdx.x;
        if (e < N_EDGES) rank[e] = atomicAdd(&cnt[dst[e] * N_REL + et[e]], 1);
    }
}

// ---------------------------------------------------------------- scanA: chunk scans + weight repack
// repack1: plain copy (RP_B blocks).  repack2: tiled GEMM W2cat x linW
// (RPT_B blocks of 16x16 output tiles, staged via LDS -> coalesced).
#define RP_B  (KTOT * C / 256)            // 576
#define RPT_B ((KTOT / 16) * (C / 16))    // 72 * 8 = 576
__global__ void scanA_kernel(const int* __restrict__ cnt, int* __restrict__ offs,
                             int* __restrict__ partials,
                             const float* __restrict__ W1, const float* __restrict__ root1,
                             const float* __restrict__ W2, const float* __restrict__ root2,
                             const float* __restrict__ linW,
                             const float* __restrict__ b2, const float* __restrict__ linb,
                             bf16* __restrict__ Bp1, bf16* __restrict__ Bp2,
                             float* __restrict__ b2p) {
    int bid = blockIdx.x;
    int t   = threadIdx.x;
    if (bid < NCHUNK) {
        __shared__ int tot[256];
        int base = bid * 1024 + t * 4;
        int v0 = (base + 0 < N_SEG) ? cnt[base + 0] : 0;
        int v1 = (base + 1 < N_SEG) ? cnt[base + 1] : 0;
        int v2 = (base + 2 < N_SEG) ? cnt[base + 2] : 0;
        int v3 = (base + 3 < N_SEG) ? cnt[base + 3] : 0;
        int tsum = v0 + v1 + v2 + v3;
        tot[t] = tsum;
        __syncthreads();
        for (int d = 1; d < 256; d <<= 1) {
            int x = tot[t];
            int y = (t >= d) ? tot[t - d] : 0;
            __syncthreads();
            tot[t] = x + y;
            __syncthreads();
        }
        int excl = tot[t] - tsum;
        if (base + 0 < N_SEG) offs[base + 0] = excl;
        if (base + 1 < N_SEG) offs[base + 1] = excl + v0;
        if (base + 2 < N_SEG) offs[base + 2] = excl + v0 + v1;
        if (base + 3 < N_SEG) offs[base + 3] = excl + v0 + v1 + v2;
        if (t == 255) partials[bid] = tot[255];
    } else if (bid < NCHUNK + RP_B) {
        int idx = (bid - NCHUNK) * 256 + t;
        int k = idx >> 7, n = idx & 127;
        float val;
        if (k < N_REL * C) val = W1[(size_t)k * C + n];
        else               val = root1[(size_t)(k - N_REL * C) * C + n];
        Bp1[frag_index(k, n)] = __float2bfloat16(val);
    } else if (bid < NCHUNK + RP_B + RPT_B) {
        // ---- tiled repack2: out(k0+ty, n0+tx) = sum_m W2cat[k0+ty][m] * linW[m][n0+tx]
        __shared__ float Wt[16][128];    // 8 KB
        __shared__ float Lt[128][16];    // 8 KB
        int tileid = bid - NCHUNK - RP_B;
        int kt = tileid >> 3;            // 0..71  (k0 = kt*16; 1024 boundary not straddled)
        int n0 = (tileid & 7) * 16;
        int k0 = kt * 16;
        const float* baseW = (k0 < N_REL * C) ? (W2 + (size_t)k0 * C)
                                              : (root2 + (size_t)(k0 - N_REL * C) * C);
#pragma unroll
        for (int r = 0; r < 8; r++) {            // 2048 elems, coalesced
            int idx = t + r * 256;
            Wt[idx >> 7][idx & 127] = baseW[idx];
        }
#pragma unroll
        for (int r = 0; r < 8; r++) {            // 2048 elems: m = idx>>4, n = idx&15
            int idx = t + r * 256;
            Lt[idx >> 4][idx & 15] = linW[(size_t)(idx >> 4) * C + n0 + (idx & 15)];
        }
        __syncthreads();
        int ty = t >> 4, tx = t & 15;
        float acc = 0.f;
#pragma unroll 8
        for (int m = 0; m < 128; m++)
            acc += Wt[ty][m] * Lt[m][tx];
        Bp2[frag_index(k0 + ty, n0 + tx)] = __float2bfloat16(acc);
    } else {
        if (t < 128) {
            float acc = linb[t];
            for (int m = 0; m < C; m++)
                acc += b2[m] * linW[(size_t)m * C + t];
            b2p[t] = acc;
        }
    }
}

// ---------------------------------------------------------------- fillB: edge fill only
// R14: the offs-finalize pass is GONE. All blocks compute the partials scan
// (needed for edge placement); block 0 additionally publishes the exclusive
// chunk-prefix table spx[NCHUNK] so fused_layer can finalize offsets on read
// (each block's offsets span <=2 chunks). Saves 1.6 MB R + 1.6 MB W + 391 blocks.
__global__ void fillB_kernel(const int* __restrict__ src, const int* __restrict__ dst,
                             const int* __restrict__ et,
                             const int* __restrict__ offs_raw,   // scanA output (chunk-local)
                             const int* __restrict__ partials,
                             const int* __restrict__ rank,
                             int* __restrict__ srcs_out,
                             int* __restrict__ spx) {
    __shared__ int s[512];
    int t = threadIdx.x;
    int bid = blockIdx.x;
    s[t] = (t < NCHUNK) ? partials[t] : 0;
    __syncthreads();
    for (int d = 1; d < 512; d <<= 1) {
        int x = s[t];
        int y = (t >= d) ? s[t - d] : 0;
        __syncthreads();
        s[t] = x + y;          // inclusive scan
        __syncthreads();
    }
    if (bid == 0 && t < NCHUNK) spx[t] = (t == 0) ? 0 : s[t - 1];   // exclusive prefix
    int e = bid * 512 + t;
    if (e < N_EDGES) {
        int seg = dst[e] * N_REL + et[e];
        int chunk = seg >> 10;
        int base = offs_raw[seg] + ((chunk == 0) ? 0 : s[chunk - 1]);
        srcs_out[base + rank[e]] = src[e];
    }
}

// ---------------------------------------------------------------- fused layer
// R14: REVERTED to the R0 body (best measured: 74.4 us) -- 16 nodes/block,
// 512 threads (8 waves), wave w owns segments [16w,16w+16), explicit 2-stage
// gather pipeline, LDS offsL, NO setprio, NO A-split, NO depth-3.
// Only change: offsL init finalizes raw chunk-local offsets with spx[]
// (RAWOFFS=1), and COPY_CSR writes FINALIZED offsets for layer 2.
template <int RELU, int OUT_F32, int COPY_CSR, int RAWOFFS>
__global__ __launch_bounds__(512, 6) void fused_layer(
        const unsigned int* __restrict__ featu,  // [N][64] bf16 pairs
        const int*   __restrict__ offs,          // raw (RAWOFFS=1) or final (0)
        const int*   __restrict__ srcs,          // [N_EDGES]
        const short8* __restrict__ Bp,           // fragment-packed bf16 weights
        const float* __restrict__ bias,          // [128] fp32
        void* __restrict__ outp,                 // [N][128] fp32 or bf16
        int* __restrict__ offs2, int* __restrict__ srcs2,   // CSR copy dst
        const int* __restrict__ spx)             // [NCHUNK] chunk prefix (RAWOFFS=1)
{
    __shared__ __align__(16) unsigned int At[16 * (A_STRIDE / 2)];  // bf16 pairs
    __shared__ int offsL[129];
    const int tid  = threadIdx.x;
    const int lane = tid & 63;
    const int w    = tid >> 6;          // 0..7
    const int v0   = blockIdx.x * 16;

    if (tid < 129) {
        int idx = v0 * 8 + tid;
        int val;
        if (RAWOFFS) val = (idx < N_SEG) ? offs[idx] + spx[idx >> 10] : N_EDGES;
        else         val = offs[idx];
        offsL[tid] = val;
    }
    if (tid < 64)  At[(tid >> 2) * (A_STRIDE / 2) + 576 + (tid & 3)] = 0u;  // pad pairs

    // relocate CSR slice (overlapped with gather latency); finalizes offsets
    if (COPY_CSR) {
        for (int i = blockIdx.x * 512 + tid; i < MV_N; i += NBLK * 512) {
            if (i < N_SEG + 1) {
                int val;
                if (RAWOFFS) val = (i < N_SEG) ? offs[i] + spx[i >> 10] : N_EDGES;
                else         val = offs[i];
                offs2[i] = val;
            } else {
                srcs2[i - (N_SEG + 1)] = srcs[i - (N_SEG + 1)];
            }
        }
    }

    // self rows -> k range [1024..1151]
    for (int q = tid; q < 16 * 64; q += 512) {
        int node = q >> 6, pch = q & 63;
        At[node * (A_STRIDE / 2) + 512 + pch] = featu[(size_t)(v0 + node) * 64 + pch];
    }
    __syncthreads();

    // ---- aggregation over wave-owned contiguous edge range (16 segments)
    {
        const int segLo = w * 16;
        const int segHi = segLo + 16;
        int curSeg = segLo;
        int segEnd = offsL[curSeg + 1];
        int i      = offsL[segLo];
        const int eend = offsL[segHi];
        float a0 = 0.f, a1 = 0.f;

        unsigned int vals[16];
        bool have = (i + 16 <= eend);
        if (have) {
            const int ib = __builtin_amdgcn_readfirstlane(i);
            int sv[16];
#pragma unroll
            for (int j = 0; j < 16; j++) sv[j] = srcs[ib + j];
#pragma unroll
            for (int j = 0; j < 16; j++) vals[j] = featu[(size_t)sv[j] * 64 + lane];
        }
        while (have) {
            const int inext = i + 16;
            const bool havenext = (inext + 16 <= eend);
            unsigned int vals2[16];
            if (havenext) {                       // prefetch batch k+1 (straight-line)
                const int ib2 = __builtin_amdgcn_readfirstlane(inext);
                int sv2[16];
#pragma unroll
                for (int j = 0; j < 16; j++) sv2[j] = srcs[ib2 + j];
#pragma unroll
                for (int j = 0; j < 16; j++) vals2[j] = featu[(size_t)sv2[j] * 64 + lane];
            }
            // fold batch k
#pragma unroll
            for (int j = 0; j < 16; j++) {
                while (i + j == segEnd) {         // flush finished segment(s)
                    int b = offsL[curSeg];
                    float inv = (segEnd > b) ? 1.0f / (float)(segEnd - b) : 0.0f;
                    union { bf162 h; unsigned int u; } cv;
                    cv.h = bf162(__float2bfloat16(a0 * inv), __float2bfloat16(a1 * inv));
                    At[(curSeg >> 3) * (A_STRIDE / 2) + (curSeg & 7) * 64 + lane] = cv.u;
                    a0 = 0.f; a1 = 0.f;
                    curSeg++;
                    segEnd = offsL[curSeg + 1];
                }
                union { bf162 h; unsigned int u; } uv; uv.u = vals[j];
                a0 += __low2float(uv.h);
                a1 += __high2float(uv.h);
            }
            i = inext;
            have = havenext;
            if (havenext) {
#pragma unroll
                for (int j = 0; j < 16; j++) vals[j] = vals2[j];
            }
        }
        // predicated tail batch (m < 16, wave-uniform)
        {
            int m = eend - i;
            const int ib = __builtin_amdgcn_readfirstlane(i);
            int sv[16];
#pragma unroll
            for (int j = 0; j < 16; j++) if (j < m) sv[j] = srcs[ib + j];
            unsigned int tvals[16];
#pragma unroll
            for (int j = 0; j < 16; j++) if (j < m) tvals[j] = featu[(size_t)sv[j] * 64 + lane];
#pragma unroll
            for (int j = 0; j < 16; j++) {
                if (j < m) {
                    while (i + j == segEnd) {
                        int b = offsL[curSeg];
                        float inv = (segEnd > b) ? 1.0f / (float)(segEnd - b) : 0.0f;
                        union { bf162 h; unsigned int u; } cv;
                        cv.h = bf162(__float2bfloat16(a0 * inv), __float2bfloat16(a1 * inv));
                        At[(curSeg >> 3) * (A_STRIDE / 2) + (curSeg & 7) * 64 + lane] = cv.u;
                        a0 = 0.f; a1 = 0.f;
                        curSeg++;
                        segEnd = offsL[curSeg + 1];
                    }
                    union { bf162 h; unsigned int u; } uv; uv.u = tvals[j];
                    a0 += __low2float(uv.h);
                    a1 += __high2float(uv.h);
                }
            }
        }
        // trailing flushes (last non-empty segment + empty tails)
        while (curSeg < segHi) {
            int b = offsL[curSeg], e2 = offsL[curSeg + 1];
            float inv = (e2 > b) ? 1.0f / (float)(e2 - b) : 0.0f;
            union { bf162 h; unsigned int u; } cv;
            cv.h = bf162(__float2bfloat16(a0 * inv), __float2bfloat16(a1 * inv));
            At[(curSeg >> 3) * (A_STRIDE / 2) + (curSeg & 7) * 64 + lane] = cv.u;
            a0 = 0.f; a1 = 0.f;
            curSeg++;
        }
    }
    __syncthreads();

    // ---- MFMA GEMM: wave w computes N-tile w (cols 16w..16w+15)
    const int quad = lane >> 4, n15 = lane & 15;
    f32x4 acc = {0.f, 0.f, 0.f, 0.f};
    const short* Ash = (const short*)At;

    short8 b0 = Bp[(size_t)(w * KC_CNT) * 64 + lane];
#pragma unroll 4
    for (int kc = 0; kc < KC_CNT; kc++) {
        short8 cb0 = b0;
        if (kc + 1 < KC_CNT)
            b0 = Bp[(size_t)(w * KC_CNT + kc + 1) * 64 + lane];
        short8 a = *reinterpret_cast<const short8*>(Ash + n15 * A_STRIDE + kc * 32 + quad * 8);
        acc = __builtin_amdgcn_mfma_f32_16x16x32_bf16(a, cb0, acc, 0, 0, 0);
    }

    // epilogue: D[m = quad*4 + r][col = w*16 + n15]
    {
        int col = w * 16 + n15;
        float bv = bias[col];
#pragma unroll
        for (int r = 0; r < 4; r++) {
            int m = quad * 4 + r;
            float v = acc[r] + bv;
            if (RELU) v = fmaxf(v, 0.f);
            if (OUT_F32) ((float*)outp)[(size_t)(v0 + m) * C + col] = v;
            else         ((bf16*)outp)[(size_t)(v0 + m) * C + col] = __float2bfloat16(v);
        }
    }
}

// ---------------------------------------------------------------- launch
// fp32 I/O. ZERO d_ws usage. Provenance:
//   d_out lo   : CSR scratch (cnt / offs_t raw / partials / spx / srcs / rank)
//   d_out hi   : x as bf16 (12.8 MB @ +11,203,584, 256B-ALIGNED) [dead after layer 1]
//   x buffer lo: h1 bf16 (12.8 MB)                            [x fp32 dead after cvt]
//   x buffer hi: packed weights Bp1/Bp2/b2p (@ +13.0 MB)      [written in scanA]
//   ei buffer  : final CSR (offs2+srcs2), copied+finalized BY layer 1
//   d_out      : final fp32 output (layer 2 writes directly)
extern "C" void kernel_launch(void* const* d_in, const int* in_sizes, int n_in,
                              void* d_out, int out_size, void* d_ws, size_t ws_size,
                              hipStream_t stream) {
    const float* x     = (const float*)d_in[0];
    const int*   ei    = (const int*)d_in[1];
    const int*   et    = (const int*)d_in[2];
    const float* W1    = (const float*)d_in[3];
    const float* root1 = (const float*)d_in[4];
    const float* b1    = (const float*)d_in[5];
    const float* W2    = (const float*)d_in[6];
    const float* root2 = (const float*)d_in[7];
    const float* b2    = (const float*)d_in[8];
    const float* linW  = (const float*)d_in[9];
    const float* linb  = (const float*)d_in[10];
    const int* src = ei;
    const int* dst = ei + N_EDGES;

    // ---- d_out scratch
    char* ob = (char*)d_out;
    int* cnt_i    = (int*)(ob + 0);          // 1,600,000 B (memset)
    int* offs_t   = (int*)(ob + 1600000);    // 1,600,000 B (raw chunk-local scans)
    int* partials = (int*)(ob + 3200000);    // 1,564 B
    int* spx      = (int*)(ob + 3201792);    // 1,564 B (exclusive chunk prefix)
    int* srcs_t   = (int*)(ob + 3203584);    // 4,000,000 B -> ends 7,203,584
    int* rank     = (int*)(ob + 7203584);    // 4,000,000 B -> ends 11,203,584
    unsigned int* xb16 = (unsigned int*)(ob + 11203584); // 256B-aligned; ends 24,003,584 < 25.6 MB

    // ---- ei buffer: final CSR (written by layer 1's copy slice)
    char* eb = (char*)d_in[1];
    int* offs2 = (int*)(eb + 0);
    int* srcs2 = (int*)(eb + 1600256);       // ends 5,600,256 < 8 MB

    // ---- x buffer: h1 low, weights high
    char* xbuf = (char*)d_in[0];
    unsigned int* h1 = (unsigned int*)xbuf;          // 12.8 MB
    bf16*  Bp1 = (bf16*)(xbuf + 13000192);           // 16B-aligned, 294,912 B
    bf16*  Bp2 = (bf16*)(xbuf + 13295360);           // 294,912 B
    float* b2p = (float*)(xbuf + 13590528);          // 512 B -> ends < 25.6 MB

    float* out = (float*)d_out;

    hipMemsetAsync(cnt_i, 0, 1600000, stream);   // cnt only
    prep_kernel<<<CVT_BLOCKS + CNT_BLOCKS, 256, 0, stream>>>(
        (const float2*)x, xb16, dst, et, cnt_i, rank);
    scanA_kernel<<<NCHUNK + RP_B + RPT_B + 1, 256, 0, stream>>>(
        cnt_i, offs_t, partials, W1, root1, W2, root2, linW, b2, linb,
        Bp1, Bp2, b2p);
    fillB_kernel<<<FE_BLK, 512, 0, stream>>>(
        src, dst, et, offs_t, partials, rank, srcs_t, spx);

    fused_layer<1, 0, 1, 1><<<NBLK, 512, 0, stream>>>(
        xb16, offs_t, srcs_t, (const short8*)Bp1, b1, (void*)h1, offs2, srcs2, spx);
    fused_layer<0, 1, 0, 0><<<NBLK, 512, 0, stream>>>(
        h1, offs2, srcs2, (const short8*)Bp2, b2p, (void*)out, nullptr, nullptr, nullptr);

    (void)in_sizes; (void)n_in; (void)out_size; (void)d_ws; (void)ws_size;
}